// Round 4
// baseline (82.833 us; speedup 1.0000x reference)
//
#include <hip/hip_runtime.h>
#include <cfloat>
#include <math.h>

namespace {
constexpr int   B      = 4;
constexpr int   N      = 8192;
constexpr int   KNN    = 16;
constexpr float EPSV   = 1e-12f;

// --- direct-path geometry (main kernel) ---
constexpr int   THREADS = 256;            // 4 waves
constexpr int   WAVES   = THREADS / 64;   // 4
constexpr int   RPW     = 4;              // query rows per wave
constexpr int   RPB     = WAVES * RPW;    // 16 rows per block
constexpr int   BPB     = N / RPB;        // 512 blocks per batch
constexpr int   GRID    = B * BPB;        // 2048
constexpr int   GROUPS  = N / 512;        // 16 candidate groups of 512

// --- fallback (LDS) geometry, proven in R2 ---
constexpr int   THREADS2 = 512;
constexpr int   WAVES2   = THREADS2 / 64; // 8
constexpr int   RPB2     = WAVES2 * RPW;  // 32
constexpr int   BPB2     = N / RPB2;      // 256
constexpr int   GRID2    = B * BPB2;      // 1024
constexpr int   TILE2    = 512;
constexpr int   NTILES2  = N / TILE2;     // 16

constexpr size_t PT4_BYTES = (size_t)B * N * sizeof(float4);   // 512 KB
}

__device__ __forceinline__ float rfl(float x) {
    return __int_as_float(__builtin_amdgcn_readfirstlane(__float_as_int(x)));
}

// ---------- prepass: (x,y,z) -> (x,y,z,|p|^2) ----------
__global__ __launch_bounds__(256)
void knn_prep(const float* __restrict__ pc, float4* __restrict__ pt4)
{
    const int i = blockIdx.x * 256 + threadIdx.x;
    if (i < B * N) {
        const float x = pc[3 * i + 0];
        const float y = pc[3 * i + 1];
        const float z = pc[3 * i + 2];
        pt4[i] = make_float4(x, y, z, fmaf(z, z, fmaf(y, y, x * x)));
    }
}

// ---------- shared merge: per-lane sorted top-4-of-8, then 16 pops ----------
// (identical math to R2; kept as a macro-free inline pattern in each kernel)
__device__ __forceinline__ void top4_of_8(const float m[8], float L[4])
{
    const float a0 = fminf(m[0], m[1]), b0 = fmaxf(m[0], m[1]);
    const float a1 = fminf(m[2], m[3]), b1 = fmaxf(m[2], m[3]);
    const float a2 = fminf(m[4], m[5]), b2 = fmaxf(m[4], m[5]);
    const float a3 = fminf(m[6], m[7]), b3 = fmaxf(m[6], m[7]);
    const float p0 = fminf(a0, a1), xP = fmaxf(a0, a1), yP = fminf(b0, b1), p3 = fmaxf(b0, b1);
    const float p1 = fminf(xP, yP), p2 = fmaxf(xP, yP);
    const float q0 = fminf(a2, a3), xQ = fmaxf(a2, a3), yQ = fminf(b2, b3), q3 = fmaxf(b2, b3);
    const float q1 = fminf(xQ, yQ), q2 = fmaxf(xQ, yQ);
    const float l0 = fminf(p0, q3), l1 = fminf(p1, q2), l2 = fminf(p2, q1), l3 = fminf(p3, q0);
    const float t0 = fminf(l0, l2), t2 = fmaxf(l0, l2);
    const float t1 = fminf(l1, l3), t3 = fmaxf(l1, l3);
    L[0] = fminf(t0, t1); L[1] = fmaxf(t0, t1);
    L[2] = fminf(t2, t3); L[3] = fmaxf(t2, t3);
}

// ---------- main kernel: global-direct, no LDS staging, no barriers ----------
template <int ATOMIC>
__global__ __launch_bounds__(THREADS)
void knn_tv_direct(const float4* __restrict__ pt4, float* __restrict__ outbuf)
{
    __shared__ float sWaveSum[WAVES];

    const int tid   = threadIdx.x;
    const int lane  = tid & 63;
    const int wave  = tid >> 6;
    const int blk   = blockIdx.x;
    const int batch = blk / BPB;
    const int row0  = (blk % BPB) * RPB + wave * RPW;

    const float4* __restrict__ b4 = pt4 + (size_t)batch * (size_t)N;

    // query scalars -> SGPR (wave-uniform); fold -2 into q, re-add |q|^2 at pop
    float qx[RPW], qy[RPW], qz[RPW], qs[RPW];
#pragma unroll
    for (int r = 0; r < RPW; ++r) {
        const float4 q = b4[row0 + r];
        qx[r] = rfl(-2.0f * q.x);
        qy[r] = rfl(-2.0f * q.y);
        qz[r] = rfl(-2.0f * q.z);
        qs[r] = rfl(q.w);
    }

    // per-(lane, slot) stream minima of v = |c|^2 - 2 q.c  (8 slots/lane)
    float m0[RPW][8];
#pragma unroll
    for (int r = 0; r < RPW; ++r)
#pragma unroll
        for (int j = 0; j < 8; ++j)
            m0[r][j] = FLT_MAX;

    int idx = lane;                      // slot j of group g reads b4[g*512 + j*64 + lane]
    for (int g = 0; g < GROUPS; ++g, idx += 512) {
        float4 a[8];
#pragma unroll
        for (int j = 0; j < 8; ++j)
            a[j] = b4[idx + j * 64];     // unit-stride 1KB per instruction, L1/L2-hit
#pragma unroll
        for (int r = 0; r < RPW; ++r) {
#pragma unroll
            for (int j = 0; j < 8; ++j) {
                const float v = fmaf(a[j].x, qx[r],
                                fmaf(a[j].y, qy[r],
                                fmaf(a[j].z, qz[r], a[j].w)));
                m0[r][j] = fminf(m0[r][j], v);
            }
        }
    }

    // per-lane sorted top-4, then 16 pops per row (k-outer so 4 chains interleave)
    float L[RPW][4];
    float racc[RPW];
#pragma unroll
    for (int r = 0; r < RPW; ++r) { top4_of_8(m0[r], L[r]); racc[r] = 0.0f; }

#pragma unroll
    for (int k = 0; k < KNN; ++k) {
#pragma unroll
        for (int r = 0; r < RPW; ++r) {
            float m = L[r][0];
            m = fminf(m, __shfl_xor(m, 1, 64));
            m = fminf(m, __shfl_xor(m, 2, 64));
            m = fminf(m, __shfl_xor(m, 4, 64));
            m = fminf(m, __shfl_xor(m, 8, 64));
            m = fminf(m, __shfl_xor(m, 16, 64));
            m = fminf(m, __shfl_xor(m, 32, 64));
            racc[r] += sqrtf(fmaxf(qs[r] + m, 0.0f) + EPSV);
            const bool take = (L[r][0] == m);
            L[r][0] = take ? L[r][1] : L[r][0];
            L[r][1] = take ? L[r][2] : L[r][1];
            L[r][2] = take ? L[r][3] : L[r][2];
            L[r][3] = take ? FLT_MAX : L[r][3];
        }
    }

    float wsum = 0.0f;
#pragma unroll
    for (int r = 0; r < RPW; ++r) wsum += racc[r];

    if (lane == 0) sWaveSum[wave] = wsum;
    __syncthreads();
    if (tid == 0) {
        float t = 0.0f;
#pragma unroll
        for (int w = 0; w < WAVES; ++w) t += sWaveSum[w];
        if (ATOMIC) atomicAdd(outbuf, t * (1.0f / (float)(B * N)));
        else        outbuf[blk] = t;
    }
}

// ---------- fallback: R2's LDS-staged kernel (unchanged, proven) ----------
template <int ATOMIC>
__global__ __launch_bounds__(THREADS2, 1)
void knn_tv_lds(const float* __restrict__ pc, float* __restrict__ outbuf)
{
    __shared__ float sX[TILE2], sY[TILE2], sZ[TILE2], sS[TILE2];
    __shared__ float sWaveSum[WAVES2];

    const int tid   = threadIdx.x;
    const int lane  = tid & 63;
    const int wave  = tid >> 6;
    const int blk   = blockIdx.x;
    const int batch = blk / BPB2;
    const int row0  = (blk % BPB2) * RPB2 + wave * RPW;

    const float* __restrict__ base = pc + (size_t)batch * (size_t)N * 3;

    float qx[RPW], qy[RPW], qz[RPW], qs[RPW];
#pragma unroll
    for (int r = 0; r < RPW; ++r) {
        const int row = row0 + r;
        const float x = base[row * 3 + 0];
        const float y = base[row * 3 + 1];
        const float z = base[row * 3 + 2];
        qx[r] = rfl(-2.0f * x); qy[r] = rfl(-2.0f * y); qz[r] = rfl(-2.0f * z);
        qs[r] = rfl(fmaf(z, z, fmaf(y, y, x * x)));
    }

    float m0[RPW][8];
#pragma unroll
    for (int r = 0; r < RPW; ++r)
#pragma unroll
        for (int c = 0; c < 8; ++c) m0[r][c] = FLT_MAX;

    for (int tile = 0; tile < NTILES2; ++tile) {
        __syncthreads();
        {
            const int p  = tid;
            const int gp = tile * TILE2 + p;
            const float x = base[gp * 3 + 0];
            const float y = base[gp * 3 + 1];
            const float z = base[gp * 3 + 2];
            sX[p] = x; sY[p] = y; sZ[p] = z;
            sS[p] = fmaf(z, z, fmaf(y, y, x * x));
        }
        __syncthreads();

        const int i0 = 4 * lane;
        const int i1 = 256 + 4 * lane;
        const float4 X0 = *(const float4*)&sX[i0], X1 = *(const float4*)&sX[i1];
        const float4 Y0 = *(const float4*)&sY[i0], Y1 = *(const float4*)&sY[i1];
        const float4 Z0 = *(const float4*)&sZ[i0], Z1 = *(const float4*)&sZ[i1];
        const float4 S0 = *(const float4*)&sS[i0], S1 = *(const float4*)&sS[i1];
        const float cx[8] = {X0.x, X0.y, X0.z, X0.w, X1.x, X1.y, X1.z, X1.w};
        const float cy[8] = {Y0.x, Y0.y, Y0.z, Y0.w, Y1.x, Y1.y, Y1.z, Y1.w};
        const float cz[8] = {Z0.x, Z0.y, Z0.z, Z0.w, Z1.x, Z1.y, Z1.z, Z1.w};
        const float cs[8] = {S0.x, S0.y, S0.z, S0.w, S1.x, S1.y, S1.z, S1.w};

#pragma unroll
        for (int r = 0; r < RPW; ++r)
#pragma unroll
            for (int c = 0; c < 8; ++c) {
                const float v = fmaf(cx[c], qx[r], fmaf(cy[c], qy[r], fmaf(cz[c], qz[r], cs[c])));
                m0[r][c] = fminf(m0[r][c], v);
            }
    }

    float L[RPW][4];
    float racc[RPW];
#pragma unroll
    for (int r = 0; r < RPW; ++r) { top4_of_8(m0[r], L[r]); racc[r] = 0.0f; }

#pragma unroll
    for (int k = 0; k < KNN; ++k) {
#pragma unroll
        for (int r = 0; r < RPW; ++r) {
            float m = L[r][0];
            m = fminf(m, __shfl_xor(m, 1, 64));
            m = fminf(m, __shfl_xor(m, 2, 64));
            m = fminf(m, __shfl_xor(m, 4, 64));
            m = fminf(m, __shfl_xor(m, 8, 64));
            m = fminf(m, __shfl_xor(m, 16, 64));
            m = fminf(m, __shfl_xor(m, 32, 64));
            racc[r] += sqrtf(fmaxf(qs[r] + m, 0.0f) + EPSV);
            const bool take = (L[r][0] == m);
            L[r][0] = take ? L[r][1] : L[r][0];
            L[r][1] = take ? L[r][2] : L[r][1];
            L[r][2] = take ? L[r][3] : L[r][2];
            L[r][3] = take ? FLT_MAX : L[r][3];
        }
    }

    float wsum = 0.0f;
#pragma unroll
    for (int r = 0; r < RPW; ++r) wsum += racc[r];

    if (lane == 0) sWaveSum[wave] = wsum;
    __syncthreads();
    if (tid == 0) {
        float t = 0.0f;
#pragma unroll
        for (int w = 0; w < WAVES2; ++w) t += sWaveSum[w];
        if (ATOMIC) atomicAdd(outbuf, t * (1.0f / (float)(B * N)));
        else        outbuf[blk] = t;
    }
}

__global__ __launch_bounds__(256)
void knn_tv_reduce(const float* __restrict__ partial, float* __restrict__ out, int n)
{
    __shared__ float s[4];
    const int tid = threadIdx.x;
    float v = 0.0f;
    for (int i = tid; i < n; i += 256) v += partial[i];
#pragma unroll
    for (int off = 1; off < 64; off <<= 1) v += __shfl_xor(v, off, 64);
    if ((tid & 63) == 0) s[tid >> 6] = v;
    __syncthreads();
    if (tid == 0) {
        const float t = s[0] + s[1] + s[2] + s[3];
        out[0] = t * (1.0f / (float)(B * N));
    }
}

extern "C" void kernel_launch(void* const* d_in, const int* in_sizes, int n_in,
                              void* d_out, int out_size, void* d_ws, size_t ws_size,
                              hipStream_t stream)
{
    const float* pc  = (const float*)d_in[0];
    float*       out = (float*)d_out;

    if (ws_size >= PT4_BYTES + GRID * sizeof(float)) {
        float4* pt4     = (float4*)d_ws;
        float*  partial = (float*)((char*)d_ws + PT4_BYTES);
        knn_prep<<<(B * N + 255) / 256, 256, 0, stream>>>(pc, pt4);
        knn_tv_direct<0><<<GRID, THREADS, 0, stream>>>(pt4, partial);
        knn_tv_reduce<<<1, 256, 0, stream>>>(partial, out, GRID);
    } else if (ws_size >= GRID2 * sizeof(float)) {
        float* partial = (float*)d_ws;
        knn_tv_lds<0><<<GRID2, THREADS2, 0, stream>>>(pc, partial);
        knn_tv_reduce<<<1, 256, 0, stream>>>(partial, out, GRID2);
    } else {
        hipMemsetAsync(d_out, 0, sizeof(float), stream);
        knn_tv_lds<1><<<GRID2, THREADS2, 0, stream>>>(pc, out);
    }
}